// Round 1
// baseline (609.909 us; speedup 1.0000x reference)
//
#include <hip/hip_runtime.h>

#define F0 21
#define F1 128
#define F2 64

// ---- degree count over dst (deg = in-degree; +1 folded into k_dinv) ----
__global__ void k_deg(const int* __restrict__ dst, float* __restrict__ deg, int E) {
    int i = blockIdx.x * blockDim.x + threadIdx.x;
    int stride = gridDim.x * blockDim.x;
    for (; i < E; i += stride) atomicAdd(&deg[dst[i]], 1.0f);
}

__global__ void k_dinv(const float* __restrict__ deg, float* __restrict__ dinv, int n) {
    int i = blockIdx.x * blockDim.x + threadIdx.x;
    if (i < n) dinv[i] = rsqrtf(deg[i] + 1.0f);
}

// ---- 21-dim edge scatter: aggx[dst] += x[src]*dinv[src]*dinv[dst];
//      also wout[src] += dinv[dst] (once per edge, lane k==0) ----
__global__ void k_edge(const int* __restrict__ src, const int* __restrict__ dst,
                       const float* __restrict__ x, const float* __restrict__ dinv,
                       float* __restrict__ wout, float* __restrict__ aggx, int E) {
    int total = E * F0;
    int i = blockIdx.x * blockDim.x + threadIdx.x;
    int stride = gridDim.x * blockDim.x;
    for (; i < total; i += stride) {
        int e = i / F0;
        int k = i - e * F0;
        int s = src[e], t = dst[e];
        float ds = dinv[s], dt = dinv[t];
        if (k == 0) atomicAdd(&wout[s], dt);
        atomicAdd(&aggx[t * F0 + k], x[s * F0 + k] * (ds * dt));
    }
}

// ---- fused: p = aggx[n] + x[n]*dinv^2 ; h1 = relu(p@W1 + b1) ;
//      sacc[j] += c[n]*h1[j]  with c[n] = dinv*wout + dinv^2 ----
__global__ void __launch_bounds__(F1) k_node(
        const float* __restrict__ x, const float* __restrict__ aggx,
        const float* __restrict__ dinv, const float* __restrict__ wout,
        const float* __restrict__ W1, const float* __restrict__ b1,
        float* __restrict__ sacc, int n) {
    __shared__ float w1s[F0 * F1];
    __shared__ float b1s[F1];
    int j = threadIdx.x;  // owns output column j (0..127)
    for (int idx = j; idx < F0 * F1; idx += F1) w1s[idx] = W1[idx];
    b1s[j] = b1[j];
    __syncthreads();

    float acc = 0.0f;
    for (int node = blockIdx.x; node < n; node += gridDim.x) {
        float di  = dinv[node];
        float di2 = di * di;
        float c   = di * wout[node] + di2;
        const float* xr = x    + (size_t)node * F0;
        const float* ar = aggx + (size_t)node * F0;
        float v = b1s[j];
        #pragma unroll
        for (int k = 0; k < F0; ++k) {
            float p = ar[k] + xr[k] * di2;   // broadcast loads (same addr all lanes)
            v += p * w1s[k * F1 + j];        // LDS: consecutive j -> conflict-free
        }
        acc += c * fmaxf(v, 0.0f);
    }
    atomicAdd(&sacc[j], acc);
}

// ---- out = b2 + (1/N) * (sacc @ W2) ----
__global__ void k_final(const float* __restrict__ sacc, const float* __restrict__ W2,
                        const float* __restrict__ b2, float* __restrict__ out, float invN) {
    int j = threadIdx.x;  // 64 threads
    float acc = 0.0f;
    #pragma unroll 8
    for (int k = 0; k < F1; ++k) acc += sacc[k] * W2[k * F2 + j];
    out[j] = b2[j] + invN * acc;
}

extern "C" void kernel_launch(void* const* d_in, const int* in_sizes, int n_in,
                              void* d_out, int out_size, void* d_ws, size_t ws_size,
                              hipStream_t stream) {
    const float* x[2]  = {(const float*)d_in[0], (const float*)d_in[1]};
    const int*   ei[2] = {(const int*)d_in[2],   (const int*)d_in[3]};
    const float* W1 = (const float*)d_in[4];
    const float* b1 = (const float*)d_in[5];
    const float* W2 = (const float*)d_in[6];
    const float* b2 = (const float*)d_in[7];
    float* out = (float*)d_out;

    const int n = in_sizes[0] / F0;   // 50000
    const int E = in_sizes[2] / 2;    // 800000

    // ws layout (floats): [deg n | wout n | aggx 21n | sacc 128 | dinv n]
    float* ws   = (float*)d_ws;
    float* deg  = ws;
    float* wout = ws + (size_t)n;
    float* aggx = ws + 2 * (size_t)n;
    float* sacc = ws + 2 * (size_t)n + (size_t)F0 * n;
    float* dinv = sacc + F1;
    size_t zero_bytes = ((size_t)23 * n + F1) * sizeof(float);  // deg..sacc contiguous

    for (int b = 0; b < 2; ++b) {
        hipMemsetAsync(ws, 0, zero_bytes, stream);
        const int* srcp = ei[b];
        const int* dstp = ei[b] + E;
        k_deg <<<1024, 256, 0, stream>>>(dstp, deg, E);
        k_dinv<<<(n + 255) / 256, 256, 0, stream>>>(deg, dinv, n);
        k_edge<<<2048, 256, 0, stream>>>(srcp, dstp, x[b], dinv, wout, aggx, E);
        k_node<<<512, F1, 0, stream>>>(x[b], aggx, dinv, wout, W1, b1, sacc, n);
        k_final<<<1, F2, 0, stream>>>(sacc, W2, b2, out + b * F2, 1.0f / (float)n);
    }
}

// Round 2
// 480.182 us; speedup vs baseline: 1.2702x; 1.2702x over previous
//
#include <hip/hip_runtime.h>

#define F0 21
#define F1 128
#define F2 64

// ---------------- per-branch pointer bundle ----------------
struct BP {
    const float* x;      // [n, F0]
    const int*   src;    // [E]
    const int*   dst;    // [E]
    int*   deg;          // [n] int; ALIASES wout
    float* wout;         // [n] float; after gather holds c[t]
    float* dinv;         // [n]
    int*   cursor;       // [n] exclusive offsets -> inclusive ends after scatter
    int*   ebuf;         // [E] src ids grouped by dst
    float* p;            // [n, F0] propagated features
    float* sacc;         // [F1]
    float* outp;         // [F2]
};

__global__ void k_deg(BP b0, BP b1, int E) {
    BP bp = blockIdx.y ? b1 : b0;
    int i = blockIdx.x * blockDim.x + threadIdx.x;
    int st = gridDim.x * blockDim.x;
    for (; i < E; i += st) atomicAdd(&bp.deg[bp.dst[i]], 1);
}

__global__ void k_dinv(BP b0, BP b1, int n) {
    BP bp = blockIdx.y ? b1 : b0;
    int i = blockIdx.x * blockDim.x + threadIdx.x;
    if (i < n) bp.dinv[i] = rsqrtf((float)bp.deg[i] + 1.0f);
}

// exclusive prefix sum of deg -> cursor; then zero wout (same memory as deg)
__global__ void __launch_bounds__(1024) k_scan(BP b0, BP b1, int n) {
    BP bp = blockIdx.y ? b1 : b0;
    __shared__ int lds[1024];
    int t = threadIdx.x;
    int chunk = (n + 1023) >> 10;
    int lo = t * chunk;
    int hi = min(lo + chunk, n);
    int s = 0;
    for (int i = lo; i < hi; ++i) s += bp.deg[i];
    lds[t] = s;
    __syncthreads();
    for (int off = 1; off < 1024; off <<= 1) {
        int v = (t >= off) ? lds[t - off] : 0;
        __syncthreads();
        lds[t] += v;
        __syncthreads();
    }
    int base = t ? lds[t - 1] : 0;
    for (int i = lo; i < hi; ++i) {
        int d = bp.deg[i];          // read BEFORE zeroing (aliased)
        bp.cursor[i] = base;
        base += d;
        bp.wout[i] = 0.0f;
    }
}

// bucket edges by dst; accumulate wout[src] += dinv[dst]
__global__ void k_scatter(BP b0, BP b1, int E) {
    BP bp = blockIdx.y ? b1 : b0;
    int i = blockIdx.x * blockDim.x + threadIdx.x;
    int st = gridDim.x * blockDim.x;
    for (; i < E; i += st) {
        int t = bp.dst[i], s = bp.src[i];
        int pos = atomicAdd(&bp.cursor[t], 1);
        bp.ebuf[pos] = s;
        atomicAdd(&bp.wout[s], bp.dinv[t]);
    }
}

// atomic-free gather: 21 lanes per node (3 nodes per wave, lane 63 idle)
// p[t] = dinv[t]*sum(dinv[s]*x[s]) + x[t]*dinv[t]^2 ; wout[t] -> c[t]
__global__ void k_gather(BP b0, BP b1, int n) {
    BP bp = blockIdx.y ? b1 : b0;
    int lane = threadIdx.x & 63;
    int sub = lane / F0;
    if (sub >= 3) return;
    int k = lane - sub * F0;
    int wid = (blockIdx.x * blockDim.x + threadIdx.x) >> 6;
    int g = wid * 3 + sub;
    int gst = ((gridDim.x * blockDim.x) >> 6) * 3;
    for (int t = g; t < n; t += gst) {
        int start = t ? bp.cursor[t - 1] : 0;
        int end = bp.cursor[t];
        float acc = 0.0f;
        for (int i = start; i < end; ++i) {
            int s = bp.ebuf[i];
            acc += bp.dinv[s] * bp.x[(size_t)s * F0 + k];
        }
        float di = bp.dinv[t];
        float di2 = di * di;
        bp.p[(size_t)t * F0 + k] = di * acc + bp.x[(size_t)t * F0 + k] * di2;
        if (k == 0) bp.wout[t] = di * bp.wout[t] + di2;   // c[t]
    }
}

// sacc[j] += sum_t c[t] * relu(p[t] @ W1[:,j] + b1[j])
__global__ void __launch_bounds__(256) k_node(BP b0, BP b1,
        const float* __restrict__ W1, const float* __restrict__ b1v, int n) {
    BP bp = blockIdx.y ? b1 : b0;
    int j = threadIdx.x & (F1 - 1);
    int half = threadIdx.x >> 7;
    float w[F0];
    #pragma unroll
    for (int k = 0; k < F0; ++k) w[k] = W1[k * F1 + j];
    float bj = b1v[j];
    float acc = 0.0f;
    for (int t = blockIdx.x * 2 + half; t < n; t += gridDim.x * 2) {
        const float* pr = bp.p + (size_t)t * F0;
        float v = bj;
        #pragma unroll
        for (int k = 0; k < F0; ++k) v += pr[k] * w[k];
        acc += bp.wout[t] * fmaxf(v, 0.0f);
    }
    __shared__ float red[256];
    red[threadIdx.x] = acc;
    __syncthreads();
    if (half == 0) atomicAdd(&bp.sacc[j], red[j] + red[j + 128]);
}

__global__ void k_final(BP b0, BP b1, const float* __restrict__ W2,
                        const float* __restrict__ b2, float invN) {
    BP bp = blockIdx.y ? b1 : b0;
    int j = threadIdx.x;
    float a = 0.0f;
    #pragma unroll 8
    for (int k = 0; k < F1; ++k) a += bp.sacc[k] * W2[k * F2 + j];
    bp.outp[j] = b2[j] + invN * a;
}

// ---------------- tier-3 fallback (round-1 algorithm, ~4.7 MB ws) ----------------
__global__ void o_deg(const int* __restrict__ dst, float* __restrict__ deg, int E) {
    int i = blockIdx.x * blockDim.x + threadIdx.x;
    int stride = gridDim.x * blockDim.x;
    for (; i < E; i += stride) atomicAdd(&deg[dst[i]], 1.0f);
}
__global__ void o_dinv(const float* __restrict__ deg, float* __restrict__ dinv, int n) {
    int i = blockIdx.x * blockDim.x + threadIdx.x;
    if (i < n) dinv[i] = rsqrtf(deg[i] + 1.0f);
}
__global__ void o_edge(const int* __restrict__ src, const int* __restrict__ dst,
                       const float* __restrict__ x, const float* __restrict__ dinv,
                       float* __restrict__ wout, float* __restrict__ aggx, int E) {
    int total = E * F0;
    int i = blockIdx.x * blockDim.x + threadIdx.x;
    int stride = gridDim.x * blockDim.x;
    for (; i < total; i += stride) {
        int e = i / F0;
        int k = i - e * F0;
        int s = src[e], t = dst[e];
        float ds = dinv[s], dt = dinv[t];
        if (k == 0) atomicAdd(&wout[s], dt);
        atomicAdd(&aggx[t * F0 + k], x[s * F0 + k] * (ds * dt));
    }
}
__global__ void __launch_bounds__(F1) o_node(
        const float* __restrict__ x, const float* __restrict__ aggx,
        const float* __restrict__ dinv, const float* __restrict__ wout,
        const float* __restrict__ W1, const float* __restrict__ b1,
        float* __restrict__ sacc, int n) {
    __shared__ float w1s[F0 * F1];
    __shared__ float b1s[F1];
    int j = threadIdx.x;
    for (int idx = j; idx < F0 * F1; idx += F1) w1s[idx] = W1[idx];
    b1s[j] = b1[j];
    __syncthreads();
    float acc = 0.0f;
    for (int node = blockIdx.x; node < n; node += gridDim.x) {
        float di = dinv[node];
        float di2 = di * di;
        float c = di * wout[node] + di2;
        const float* xr = x + (size_t)node * F0;
        const float* ar = aggx + (size_t)node * F0;
        float v = b1s[j];
        #pragma unroll
        for (int k = 0; k < F0; ++k) v += (ar[k] + xr[k] * di2) * w1s[k * F1 + j];
        acc += c * fmaxf(v, 0.0f);
    }
    atomicAdd(&sacc[j], acc);
}
__global__ void o_final(const float* __restrict__ sacc, const float* __restrict__ W2,
                        const float* __restrict__ b2, float* __restrict__ out, float invN) {
    int j = threadIdx.x;
    float acc = 0.0f;
    #pragma unroll 8
    for (int k = 0; k < F1; ++k) acc += sacc[k] * W2[k * F2 + j];
    out[j] = b2[j] + invN * acc;
}

extern "C" void kernel_launch(void* const* d_in, const int* in_sizes, int n_in,
                              void* d_out, int out_size, void* d_ws, size_t ws_size,
                              hipStream_t stream) {
    const float* W1 = (const float*)d_in[4];
    const float* b1 = (const float*)d_in[5];
    const float* W2 = (const float*)d_in[6];
    const float* b2 = (const float*)d_in[7];
    float* out = (float*)d_out;

    const int n = in_sizes[0] / F0;   // 50000
    const int E = in_sizes[2] / 2;    // 800000
    const float invN = 1.0f / (float)n;

    // per-branch layout
    size_t o = 0;
    auto alloc = [&](size_t bytes) { size_t r = o; o += (bytes + 255) & ~(size_t)255; return r; };
    size_t o_degw = alloc((size_t)n * 4);
    size_t o_di   = alloc((size_t)n * 4);
    size_t o_cur  = alloc((size_t)n * 4);
    size_t o_eb   = alloc((size_t)E * 4);
    size_t o_p    = alloc((size_t)n * F0 * 4);
    size_t branch_bytes = o;
    size_t sacc_bytes = 2 * F1 * sizeof(float);
    size_t need2 = 2 * branch_bytes + sacc_bytes;
    size_t need1 = branch_bytes + sacc_bytes;

    char* ws = (char*)d_ws;

    auto mk = [&](int b, char* base, float* sacc, float* outp) {
        BP bp;
        bp.x = (const float*)d_in[b];
        const int* e = (const int*)d_in[2 + b];
        bp.src = e;
        bp.dst = e + E;
        bp.deg    = (int*)(base + o_degw);
        bp.wout   = (float*)(base + o_degw);
        bp.dinv   = (float*)(base + o_di);
        bp.cursor = (int*)(base + o_cur);
        bp.ebuf   = (int*)(base + o_eb);
        bp.p      = (float*)(base + o_p);
        bp.sacc = sacc;
        bp.outp = outp;
        return bp;
    };

    if (ws_size >= need2) {
        // fused two-branch path
        float* sacc = (float*)(ws + 2 * branch_bytes);
        BP bp0 = mk(0, ws, sacc, out);
        BP bp1 = mk(1, ws + branch_bytes, sacc + F1, out + F2);
        hipMemsetAsync(ws + o_degw, 0, (size_t)n * 4, stream);
        hipMemsetAsync(ws + branch_bytes + o_degw, 0, (size_t)n * 4, stream);
        hipMemsetAsync(sacc, 0, sacc_bytes, stream);
        k_deg    <<<dim3(512, 2), 256, 0, stream>>>(bp0, bp1, E);
        k_dinv   <<<dim3((n + 255) / 256, 2), 256, 0, stream>>>(bp0, bp1, n);
        k_scan   <<<dim3(1, 2), 1024, 0, stream>>>(bp0, bp1, n);
        k_scatter<<<dim3(512, 2), 256, 0, stream>>>(bp0, bp1, E);
        k_gather <<<dim3(2048, 2), 256, 0, stream>>>(bp0, bp1, n);
        k_node   <<<dim3(128, 2), 256, 0, stream>>>(bp0, bp1, W1, b1, n);
        k_final  <<<dim3(1, 2), F2, 0, stream>>>(bp0, bp1, W2, b2, invN);
    } else if (ws_size >= need1) {
        // sequential branches, shared workspace
        float* sacc = (float*)(ws + branch_bytes);
        for (int b = 0; b < 2; ++b) {
            BP bp = mk(b, ws, sacc, out + b * F2);
            hipMemsetAsync(ws + o_degw, 0, (size_t)n * 4, stream);
            hipMemsetAsync(sacc, 0, F1 * sizeof(float), stream);
            k_deg    <<<dim3(512, 1), 256, 0, stream>>>(bp, bp, E);
            k_dinv   <<<dim3((n + 255) / 256, 1), 256, 0, stream>>>(bp, bp, n);
            k_scan   <<<dim3(1, 1), 1024, 0, stream>>>(bp, bp, n);
            k_scatter<<<dim3(512, 1), 256, 0, stream>>>(bp, bp, E);
            k_gather <<<dim3(2048, 1), 256, 0, stream>>>(bp, bp, n);
            k_node   <<<dim3(128, 1), 256, 0, stream>>>(bp, bp, W1, b1, n);
            k_final  <<<dim3(1, 1), F2, 0, stream>>>(bp, bp, W2, b2, invN);
        }
    } else {
        // tier-3: round-1 algorithm (atomic scatter), ~4.7 MB
        float* wsf  = (float*)d_ws;
        float* deg  = wsf;
        float* wout = wsf + (size_t)n;
        float* aggx = wsf + 2 * (size_t)n;
        float* sacc = wsf + 2 * (size_t)n + (size_t)F0 * n;
        float* dinv = sacc + F1;
        size_t zero_bytes = ((size_t)23 * n + F1) * sizeof(float);
        for (int b = 0; b < 2; ++b) {
            hipMemsetAsync(wsf, 0, zero_bytes, stream);
            const int* srcp = (const int*)d_in[2 + b];
            const int* dstp = srcp + E;
            const float* x = (const float*)d_in[b];
            o_deg <<<1024, 256, 0, stream>>>(dstp, deg, E);
            o_dinv<<<(n + 255) / 256, 256, 0, stream>>>(deg, dinv, n);
            o_edge<<<2048, 256, 0, stream>>>(srcp, dstp, x, dinv, wout, aggx, E);
            o_node<<<512, F1, 0, stream>>>(x, aggx, dinv, wout, W1, b1, sacc, n);
            o_final<<<1, F2, 0, stream>>>(sacc, W2, b2, out + b * F2, invN);
        }
    }
}

// Round 3
// 427.154 us; speedup vs baseline: 1.4278x; 1.1241x over previous
//
#include <hip/hip_runtime.h>

#define F0 21
#define F1 128
#define F2 64
#define NPB 98          // nodes per bucket (t_local fits 7 bits)
#define MAXB 512        // bucket array size; NB = ceil(n/NPB) must be <= MAXB
#define BIN_TPB 1024
#define BIN_EPT 4       // edges per thread in k_bin
#define BIN_EPB (BIN_TPB * BIN_EPT)   // 4096 edges per block -> rank fits 12 bits

// ---------------- per-branch pointer bundle ----------------
struct BP {
    const float* x;        // [n, F0]
    const int*   src;      // [E]
    const int*   dst;      // [E]
    int*   deg;            // [n]
    float* wout;           // [n] sum of dinv[dst] over out-edges of node
    float* dinv;           // [n]
    int*   bbase;          // [MAXB+1] exclusive bucket offsets (stable)
    int*   bcur;           // [MAXB]   working cursors
    unsigned int* ebuf;    // [E] packed (t_local<<17)|src, grouped by bucket
    float* sacc;           // [F1]
    float* outp;           // [F2]
};

__global__ void k_deg(BP b0, BP b1, int E) {
    BP bp = blockIdx.y ? b1 : b0;
    int i = blockIdx.x * blockDim.x + threadIdx.x;
    int st = gridDim.x * blockDim.x;
    for (; i < E; i += st) atomicAdd(&bp.deg[bp.dst[i]], 1);
}

__global__ void k_dinv(BP b0, BP b1, int n) {
    BP bp = blockIdx.y ? b1 : b0;
    int i = blockIdx.x * blockDim.x + threadIdx.x;
    if (i < n) bp.dinv[i] = rsqrtf((float)bp.deg[i] + 1.0f);
}

// bucket base offsets from deg (bucket b = nodes [b*NPB, b*NPB+NPB))
__global__ void __launch_bounds__(MAXB) k_scan(BP b0, BP b1, int n) {
    BP bp = blockIdx.y ? b1 : b0;
    __shared__ int lds[MAXB];
    int t = threadIdx.x;
    int lo = t * NPB, hi = min(lo + NPB, n);
    int s = 0;
    for (int i = lo; i < hi; ++i) s += bp.deg[i];
    lds[t] = s;
    __syncthreads();
    for (int off = 1; off < MAXB; off <<= 1) {
        int v = (t >= off) ? lds[t - off] : 0;
        __syncthreads();
        lds[t] += v;
        __syncthreads();
    }
    int excl = lds[t] - s;
    bp.bbase[t] = excl;
    bp.bcur[t]  = excl;
    if (t == MAXB - 1) bp.bbase[MAXB] = lds[t];
}

// counting-sort edges into buckets; LDS ranks + 1 global atomic per (block,bucket).
// Also wout[src] += dinv[dst] (fire-and-forget atomic).
__global__ void __launch_bounds__(BIN_TPB) k_bin(BP b0, BP b1, int E) {
    BP bp = blockIdx.y ? b1 : b0;
    __shared__ int hist[MAXB];
    __shared__ int base[MAXB];
    int tid = threadIdx.x;
    if (tid < MAXB) hist[tid] = 0;
    __syncthreads();
    unsigned int pk[BIN_EPT], br[BIN_EPT];
    int e0 = blockIdx.x * BIN_EPB;
    #pragma unroll
    for (int i = 0; i < BIN_EPT; ++i) {
        int e = e0 + i * BIN_TPB + tid;
        if (e < E) {
            int s = bp.src[e], t = bp.dst[e];
            unsigned int b = (unsigned int)t / NPB;
            int r = atomicAdd(&hist[b], 1);                       // LDS atomic
            pk[i] = ((unsigned int)(t - (int)b * NPB) << 17) | (unsigned int)s;
            br[i] = (b << 12) | (unsigned int)r;                  // r < 4096
            atomicAdd(&bp.wout[s], bp.dinv[t]);                   // no-return
        }
    }
    __syncthreads();
    if (tid < MAXB) {
        int c = hist[tid];
        base[tid] = c ? atomicAdd(&bp.bcur[tid], c) : 0;
    }
    __syncthreads();
    #pragma unroll
    for (int i = 0; i < BIN_EPT; ++i) {
        int e = e0 + i * BIN_TPB + tid;
        if (e < E) {
            unsigned int b = br[i] >> 12, r = br[i] & 4095u;
            bp.ebuf[base[b] + r] = pk[i];
        }
    }
}

// one block per bucket: LDS-aggregate p, then fused relu(p@W1+b1) weighted-reduce.
__global__ void __launch_bounds__(256) k_agg(BP b0, BP b1,
        const float* __restrict__ W1, const float* __restrict__ b1v, int n) {
    BP bp = blockIdx.y ? b1 : b0;
    __shared__ float agg[NPB * F0];   // 8232 B
    __shared__ float w1s[F0 * F1];    // 10752 B
    __shared__ float dls[NPB];
    __shared__ float red[256];
    int tid = threadIdx.x;
    int node0 = blockIdx.x * NPB;
    int nn = min(NPB, n - node0);
    for (int i = tid; i < F0 * F1; i += 256) w1s[i] = W1[i];
    for (int i = tid; i < NPB * F0; i += 256) agg[i] = 0.0f;
    if (tid < nn) dls[tid] = bp.dinv[node0 + tid];
    __syncthreads();
    int s0 = bp.bbase[blockIdx.x], s1 = bp.bbase[blockIdx.x + 1];
    for (int e = s0 + tid; e < s1; e += 256) {
        unsigned int u = bp.ebuf[e];
        int s  = (int)(u & 0x1FFFFu);
        int tl = (int)(u >> 17);
        float ds = bp.dinv[s];
        const float* xr = bp.x + (size_t)s * F0;
        float* ag = agg + tl * F0;
        #pragma unroll
        for (int k = 0; k < F0; ++k) atomicAdd(&ag[k], ds * xr[k]);  // LDS atomic
    }
    __syncthreads();
    int j = tid & (F1 - 1), half = tid >> 7;
    float bj = b1v[j];
    float acc = 0.0f;
    for (int tl = half; tl < nn; tl += 2) {
        float di = dls[tl], di2 = di * di;
        const float* xt = bp.x + (size_t)(node0 + tl) * F0;
        const float* ag = agg + tl * F0;
        float v = bj;
        #pragma unroll
        for (int k = 0; k < F0; ++k) v += (di * ag[k] + xt[k] * di2) * w1s[k * F1 + j];
        float c = di * bp.wout[node0 + tl] + di2;
        acc += c * fmaxf(v, 0.0f);
    }
    red[tid] = acc;
    __syncthreads();
    if (half == 0) atomicAdd(&bp.sacc[j], red[j] + red[j + F1]);
}

__global__ void k_final(BP b0, BP b1, const float* __restrict__ W2,
                        const float* __restrict__ b2, float invN) {
    BP bp = blockIdx.y ? b1 : b0;
    int j = threadIdx.x;
    float a = 0.0f;
    #pragma unroll 8
    for (int k = 0; k < F1; ++k) a += bp.sacc[k] * W2[k * F2 + j];
    bp.outp[j] = b2[j] + invN * a;
}

// ---------------- fallback (round-1 algorithm, ~4.7 MB ws) ----------------
__global__ void o_deg(const int* __restrict__ dst, float* __restrict__ deg, int E) {
    int i = blockIdx.x * blockDim.x + threadIdx.x;
    int stride = gridDim.x * blockDim.x;
    for (; i < E; i += stride) atomicAdd(&deg[dst[i]], 1.0f);
}
__global__ void o_dinv(const float* __restrict__ deg, float* __restrict__ dinv, int n) {
    int i = blockIdx.x * blockDim.x + threadIdx.x;
    if (i < n) dinv[i] = rsqrtf(deg[i] + 1.0f);
}
__global__ void o_edge(const int* __restrict__ src, const int* __restrict__ dst,
                       const float* __restrict__ x, const float* __restrict__ dinv,
                       float* __restrict__ wout, float* __restrict__ aggx, int E) {
    int total = E * F0;
    int i = blockIdx.x * blockDim.x + threadIdx.x;
    int stride = gridDim.x * blockDim.x;
    for (; i < total; i += stride) {
        int e = i / F0;
        int k = i - e * F0;
        int s = src[e], t = dst[e];
        float ds = dinv[s], dt = dinv[t];
        if (k == 0) atomicAdd(&wout[s], dt);
        atomicAdd(&aggx[t * F0 + k], x[s * F0 + k] * (ds * dt));
    }
}
__global__ void __launch_bounds__(F1) o_node(
        const float* __restrict__ x, const float* __restrict__ aggx,
        const float* __restrict__ dinv, const float* __restrict__ wout,
        const float* __restrict__ W1, const float* __restrict__ b1,
        float* __restrict__ sacc, int n) {
    __shared__ float w1s[F0 * F1];
    __shared__ float b1s[F1];
    int j = threadIdx.x;
    for (int idx = j; idx < F0 * F1; idx += F1) w1s[idx] = W1[idx];
    b1s[j] = b1[j];
    __syncthreads();
    float acc = 0.0f;
    for (int node = blockIdx.x; node < n; node += gridDim.x) {
        float di = dinv[node];
        float di2 = di * di;
        float c = di * wout[node] + di2;
        const float* xr = x + (size_t)node * F0;
        const float* ar = aggx + (size_t)node * F0;
        float v = b1s[j];
        #pragma unroll
        for (int k = 0; k < F0; ++k) v += (ar[k] + xr[k] * di2) * w1s[k * F1 + j];
        acc += c * fmaxf(v, 0.0f);
    }
    atomicAdd(&sacc[j], acc);
}
__global__ void o_final(const float* __restrict__ sacc, const float* __restrict__ W2,
                        const float* __restrict__ b2, float* __restrict__ out, float invN) {
    int j = threadIdx.x;
    float acc = 0.0f;
    #pragma unroll 8
    for (int k = 0; k < F1; ++k) acc += sacc[k] * W2[k * F2 + j];
    out[j] = b2[j] + invN * acc;
}

extern "C" void kernel_launch(void* const* d_in, const int* in_sizes, int n_in,
                              void* d_out, int out_size, void* d_ws, size_t ws_size,
                              hipStream_t stream) {
    const float* W1 = (const float*)d_in[4];
    const float* b1 = (const float*)d_in[5];
    const float* W2 = (const float*)d_in[6];
    const float* b2 = (const float*)d_in[7];
    float* out = (float*)d_out;

    const int n = in_sizes[0] / F0;   // 50000
    const int E = in_sizes[2] / 2;    // 800000
    const int NB = (n + NPB - 1) / NPB;
    const float invN = 1.0f / (float)n;

    // per-branch layout (deg,wout contiguous for one memset)
    size_t o = 0;
    auto alloc = [&](size_t bytes) { size_t r = o; o += (bytes + 255) & ~(size_t)255; return r; };
    size_t o_degw = alloc((size_t)n * 8);            // deg[n] + wout[n]
    size_t o_di   = alloc((size_t)n * 4);
    size_t o_bb   = alloc((size_t)(MAXB + 1) * 4);
    size_t o_bc   = alloc((size_t)MAXB * 4);
    size_t o_eb   = alloc((size_t)E * 4);
    size_t branch_bytes = o;
    size_t sacc_bytes = 2 * F1 * sizeof(float);
    size_t need = 2 * branch_bytes + sacc_bytes;

    char* ws = (char*)d_ws;

    bool packable = (n <= 131071) && (NB <= MAXB) && (E > 0);

    if (packable && ws_size >= need) {
        float* sacc = (float*)(ws + 2 * branch_bytes);
        auto mk = [&](int b) {
            char* base = ws + (size_t)b * branch_bytes;
            BP bp;
            bp.x = (const float*)d_in[b];
            const int* e = (const int*)d_in[2 + b];
            bp.src = e;
            bp.dst = e + E;
            bp.deg  = (int*)(base + o_degw);
            bp.wout = (float*)(base + o_degw) + n;
            bp.dinv = (float*)(base + o_di);
            bp.bbase = (int*)(base + o_bb);
            bp.bcur  = (int*)(base + o_bc);
            bp.ebuf  = (unsigned int*)(base + o_eb);
            bp.sacc = sacc + b * F1;
            bp.outp = out + b * F2;
            return bp;
        };
        BP bp0 = mk(0), bp1 = mk(1);
        hipMemsetAsync(ws + o_degw, 0, (size_t)n * 8, stream);
        hipMemsetAsync(ws + branch_bytes + o_degw, 0, (size_t)n * 8, stream);
        hipMemsetAsync(sacc, 0, sacc_bytes, stream);
        k_deg  <<<dim3(1024, 2), 256, 0, stream>>>(bp0, bp1, E);
        k_dinv <<<dim3((n + 255) / 256, 2), 256, 0, stream>>>(bp0, bp1, n);
        k_scan <<<dim3(1, 2), MAXB, 0, stream>>>(bp0, bp1, n);
        k_bin  <<<dim3((E + BIN_EPB - 1) / BIN_EPB, 2), BIN_TPB, 0, stream>>>(bp0, bp1, E);
        k_agg  <<<dim3(NB, 2), 256, 0, stream>>>(bp0, bp1, W1, b1, n);
        k_final<<<dim3(1, 2), F2, 0, stream>>>(bp0, bp1, W2, b2, invN);
    } else {
        // fallback: round-1 algorithm (atomic scatter), ~4.7 MB
        float* wsf  = (float*)d_ws;
        float* deg  = wsf;
        float* wout = wsf + (size_t)n;
        float* aggx = wsf + 2 * (size_t)n;
        float* sacc = wsf + 2 * (size_t)n + (size_t)F0 * n;
        float* dinv = sacc + F1;
        size_t zero_bytes = ((size_t)23 * n + F1) * sizeof(float);
        for (int b = 0; b < 2; ++b) {
            hipMemsetAsync(wsf, 0, zero_bytes, stream);
            const int* srcp = (const int*)d_in[2 + b];
            const int* dstp = srcp + E;
            const float* x = (const float*)d_in[b];
            o_deg <<<1024, 256, 0, stream>>>(dstp, deg, E);
            o_dinv<<<(n + 255) / 256, 256, 0, stream>>>(deg, dinv, n);
            o_edge<<<2048, 256, 0, stream>>>(srcp, dstp, x, dinv, wout, aggx, E);
            o_node<<<512, F1, 0, stream>>>(x, aggx, dinv, wout, W1, b1, sacc, n);
            o_final<<<1, F2, 0, stream>>>(sacc, W2, b2, out + b * F2, invN);
        }
    }
}

// Round 5
// 314.600 us; speedup vs baseline: 1.9387x; 1.3578x over previous
//
#include <hip/hip_runtime.h>
#include <hip/hip_fp16.h>

#define F0 21
#define F1 128
#define F2 64
#define NPB 49            // nodes per bucket; NB = ceil(n/NPB) must be <= MAXB
#define MAXB 1024
#define IDM 0x1FFFFu      // 17-bit node id mask (n < 131072)
#define BIN_TPB 1024
#define BIN_EPT 2
#define BIN_EPB (BIN_TPB * BIN_EPT)   // 2048 edges/block; rank < 4096 guaranteed

// quadrant bundle: (branch, keying system). sys0 = key by dst, sys1 = key by src
struct QP {
    const int* key;       // [E]
    const int* pay;       // [E]
    int*       bcnt;      // [MAXB]
    int*       bbase;     // [MAXB+1]
    int*       bcur;      // [MAXB]
    unsigned*  ebuf;      // [E] packed (local<<17)|payload_id
};

// per-branch bundle for the later kernels
struct GP {
    const float*    x;     // [n, F0]
    const unsigned* ebd;   // dst-keyed ebuf
    const int*      bbd;   // dst-keyed bbase
    const unsigned* ebs;   // src-keyed ebuf
    const int*      bbs;   // src-keyed bbase
    float*          dinv;  // [n]
    float*          wout;  // [n]
    __half*         y;     // [n*24] fp16 dinv[s]*x[s][k], padded to 24
    float*          part;  // [NB*F1]
    float*          outp;  // [F2]
};

__device__ __forceinline__ QP pickq(QP a, QP b, QP c, QP d) {
    unsigned q = blockIdx.y;
    return q == 0 ? a : q == 1 ? b : q == 2 ? c : d;
}

// ---- phase A: bucket histogram (LDS) + small global merge ----
__global__ void __launch_bounds__(BIN_TPB) k_binA(QP a, QP b, QP c, QP d, int E) {
    QP q = pickq(a, b, c, d);
    __shared__ int h[MAXB];
    int tid = threadIdx.x;
    h[tid] = 0;
    __syncthreads();
    for (int i = blockIdx.x * BIN_TPB + tid; i < E; i += gridDim.x * BIN_TPB)
        atomicAdd(&h[(unsigned)q.key[i] / NPB], 1);
    __syncthreads();
    int v = h[tid];
    if (v) atomicAdd(&q.bcnt[tid], v);
}

// ---- exclusive scan of bucket counts ----
__global__ void __launch_bounds__(MAXB) k_scan(QP a, QP b, QP c, QP d) {
    QP q = pickq(a, b, c, d);
    __shared__ int lds[MAXB];
    int tid = threadIdx.x;
    int v = q.bcnt[tid];
    lds[tid] = v;
    __syncthreads();
    for (int off = 1; off < MAXB; off <<= 1) {
        int t = (tid >= off) ? lds[tid - off] : 0;
        __syncthreads();
        lds[tid] += t;
        __syncthreads();
    }
    int excl = lds[tid] - v;
    q.bbase[tid] = excl;
    q.bcur[tid] = excl;
    if (tid == MAXB - 1) q.bbase[MAXB] = lds[tid];
}

// ---- phase B: scatter edges into buckets (LDS ranks, 1 reservation/(block,bucket)) ----
__global__ void __launch_bounds__(BIN_TPB) k_binB(QP a, QP b, QP c, QP d, int E) {
    QP q = pickq(a, b, c, d);
    __shared__ int h[MAXB];
    __shared__ int base[MAXB];
    int tid = threadIdx.x;
    h[tid] = 0;
    __syncthreads();
    int e0 = blockIdx.x * BIN_EPB;
    unsigned pk[BIN_EPT], br[BIN_EPT];
    #pragma unroll
    for (int i = 0; i < BIN_EPT; ++i) {
        int e = e0 + i * BIN_TPB + tid;
        if (e < E) {
            int k = q.key[e], p = q.pay[e];
            unsigned bk = (unsigned)k / NPB;
            int r = atomicAdd(&h[bk], 1);
            pk[i] = ((unsigned)(k - (int)bk * NPB) << 17) | (unsigned)p;
            br[i] = (bk << 12) | (unsigned)r;
        }
    }
    __syncthreads();
    int c0 = h[tid];
    if (c0) base[tid] = atomicAdd(&q.bcur[tid], c0);
    __syncthreads();
    #pragma unroll
    for (int i = 0; i < BIN_EPT; ++i) {
        int e = e0 + i * BIN_TPB + tid;
        if (e < E) {
            unsigned bk = br[i] >> 12, r = br[i] & 4095u;
            q.ebuf[base[bk] + r] = pk[i];
        }
    }
}

// ---- per dst-bucket degree count from sorted edges -> dinv (no global atomics) ----
__global__ void __launch_bounds__(256) k_deg2(GP g0, GP g1, int n) {
    GP g = blockIdx.y ? g1 : g0;
    __shared__ int cnt[NPB];
    int tid = threadIdx.x;
    if (tid < NPB) cnt[tid] = 0;
    __syncthreads();
    int s0 = g.bbd[blockIdx.x], s1 = g.bbd[blockIdx.x + 1];
    for (int e = s0 + tid; e < s1; e += 256) atomicAdd(&cnt[g.ebd[e] >> 17], 1);
    __syncthreads();
    int node = blockIdx.x * NPB + tid;
    if (tid < NPB && node < n) g.dinv[node] = rsqrtf(1.0f + (float)cnt[tid]);
}

// ---- y[s][k] = fp16(dinv[s] * x[s][k]), rows padded to 24 halfs ----
__global__ void __launch_bounds__(256) k_prep(GP g0, GP g1, int n) {
    GP g = blockIdx.y ? g1 : g0;
    int i = blockIdx.x * 256 + threadIdx.x;
    int total = n * 24;
    if (i < total) {
        int s = i / 24;
        int k = i - s * 24;
        float v = (k < F0) ? g.dinv[s] * g.x[(size_t)s * F0 + k] : 0.0f;
        g.y[i] = __float2half(v);
    }
}

// ---- per src-bucket: wout[s] = sum(dinv[dst]) from src-sorted edges ----
__global__ void __launch_bounds__(256) k_wout(GP g0, GP g1, int n) {
    GP g = blockIdx.y ? g1 : g0;
    __shared__ float wl[NPB];
    int tid = threadIdx.x;
    if (tid < NPB) wl[tid] = 0.0f;
    __syncthreads();
    int s0 = g.bbs[blockIdx.x], s1 = g.bbs[blockIdx.x + 1];
    for (int e = s0 + tid; e < s1; e += 256) {
        unsigned u = g.ebs[e];
        atomicAdd(&wl[u >> 17], g.dinv[u & IDM]);
    }
    __syncthreads();
    int node = blockIdx.x * NPB + tid;
    if (tid < NPB && node < n) g.wout[node] = wl[tid];
}

// ---- main: per dst-bucket LDS aggregation of y rows + fused relu(p@W1+b1) reduce ----
__global__ void __launch_bounds__(256) k_agg(GP g0, GP g1,
        const float* __restrict__ W1, const float* __restrict__ b1v, int n) {
    GP g = blockIdx.y ? g1 : g0;
    __shared__ float agg[NPB * F0];   // 4116 B
    __shared__ float w1s[F0 * F1];    // 10752 B
    __shared__ float red[256];
    int tid = threadIdx.x;
    for (int i = tid; i < F0 * F1; i += 256) w1s[i] = W1[i];
    for (int i = tid; i < NPB * F0; i += 256) agg[i] = 0.0f;
    __syncthreads();
    int s0 = g.bbd[blockIdx.x], s1 = g.bbd[blockIdx.x + 1];
    const uint4* yb = (const uint4*)g.y;     // 3 x uint4 per 24-half row
    for (int e = s0 + tid; e < s1; e += 256) {
        unsigned u = g.ebd[e];
        int s = (int)(u & IDM);
        int tl = (int)(u >> 17);
        uint4 A = yb[s * 3 + 0];
        uint4 B = yb[s * 3 + 1];
        uint4 C = yb[s * 3 + 2];
        float* ag = agg + tl * F0;
        const unsigned w[12] = {A.x, A.y, A.z, A.w, B.x, B.y, B.z, B.w, C.x, C.y, C.z, C.w};
        #pragma unroll
        for (int m = 0; m < 10; ++m) {
            __half2 hh = *reinterpret_cast<const __half2*>(&w[m]);
            float2 ff = __half22float2(hh);
            atomicAdd(&ag[2 * m], ff.x);
            atomicAdd(&ag[2 * m + 1], ff.y);
        }
        {   // element 20
            __half2 hh = *reinterpret_cast<const __half2*>(&w[10]);
            atomicAdd(&ag[20], __low2float(hh));
        }
    }
    __syncthreads();
    int j = tid & (F1 - 1), half = tid >> 7;
    int node0 = blockIdx.x * NPB;
    int nn = min(NPB, n - node0);
    float bj = b1v[j];
    float acc = 0.0f;
    for (int tl = half; tl < nn; tl += 2) {
        int node = node0 + tl;
        float di = g.dinv[node];                       // broadcast load
        float co = di * g.wout[node] + di * di;
        const __half* yt = g.y + (size_t)node * 24;    // self term: di*y[t] = di^2*x[t]
        float v = bj;
        #pragma unroll
        for (int k = 0; k < F0; ++k) {
            float p = di * (agg[tl * F0 + k] + __half2float(yt[k]));
            v += p * w1s[k * F1 + j];
        }
        acc += co * fmaxf(v, 0.0f);
    }
    red[tid] = acc;
    __syncthreads();
    if (half == 0) g.part[(size_t)blockIdx.x * F1 + j] = red[j] + red[j + F1];
}

// ---- reduce part over buckets, then out = b2 + invN * (sacc @ W2) ----
__global__ void __launch_bounds__(1024) k_fin(GP g0, GP g1,
        const float* __restrict__ W2, const float* __restrict__ b2,
        float invN, int NB) {
    GP g = blockIdx.y ? g1 : g0;
    __shared__ float red[1024];
    __shared__ float sv[F1];
    int tid = threadIdx.x;
    int j = tid & (F1 - 1), h = tid >> 7;   // 8 slices
    float a = 0.0f;
    for (int r = h; r < NB; r += 8) a += g.part[(size_t)r * F1 + j];
    red[tid] = a;
    __syncthreads();
    for (int s = 4; s >= 1; s >>= 1) {
        if (h < s) red[tid] += red[tid + s * F1];
        __syncthreads();
    }
    if (tid < F1) sv[tid] = red[tid];
    __syncthreads();
    if (tid < F2) {
        float o = 0.0f;
        #pragma unroll 8
        for (int k = 0; k < F1; ++k) o += sv[k] * W2[k * F2 + tid];
        g.outp[tid] = b2[tid] + invN * o;
    }
}

// ---------------- fallback (round-1 algorithm, ~4.7 MB ws) ----------------
__global__ void o_deg(const int* __restrict__ dst, float* __restrict__ deg, int E) {
    int i = blockIdx.x * blockDim.x + threadIdx.x;
    int stride = gridDim.x * blockDim.x;
    for (; i < E; i += stride) atomicAdd(&deg[dst[i]], 1.0f);
}
__global__ void o_dinv(const float* __restrict__ deg, float* __restrict__ dinv, int n) {
    int i = blockIdx.x * blockDim.x + threadIdx.x;
    if (i < n) dinv[i] = rsqrtf(deg[i] + 1.0f);
}
__global__ void o_edge(const int* __restrict__ src, const int* __restrict__ dst,
                       const float* __restrict__ x, const float* __restrict__ dinv,
                       float* __restrict__ wout, float* __restrict__ aggx, int E) {
    int total = E * F0;
    int i = blockIdx.x * blockDim.x + threadIdx.x;
    int stride = gridDim.x * blockDim.x;
    for (; i < total; i += stride) {
        int e = i / F0;
        int k = i - e * F0;
        int s = src[e], t = dst[e];
        float ds = dinv[s], dt = dinv[t];
        if (k == 0) atomicAdd(&wout[s], dt);
        atomicAdd(&aggx[t * F0 + k], x[s * F0 + k] * (ds * dt));
    }
}
__global__ void __launch_bounds__(F1) o_node(
        const float* __restrict__ x, const float* __restrict__ aggx,
        const float* __restrict__ dinv, const float* __restrict__ wout,
        const float* __restrict__ W1, const float* __restrict__ b1,
        float* __restrict__ sacc, int n) {
    __shared__ float w1s[F0 * F1];
    __shared__ float b1s[F1];
    int j = threadIdx.x;
    for (int idx = j; idx < F0 * F1; idx += F1) w1s[idx] = W1[idx];
    b1s[j] = b1[j];
    __syncthreads();
    float acc = 0.0f;
    for (int node = blockIdx.x; node < n; node += gridDim.x) {
        float di = dinv[node];
        float di2 = di * di;
        float c = di * wout[node] + di2;
        const float* xr = x + (size_t)node * F0;
        const float* ar = aggx + (size_t)node * F0;
        float v = b1s[j];
        #pragma unroll
        for (int k = 0; k < F0; ++k) v += (ar[k] + xr[k] * di2) * w1s[k * F1 + j];
        acc += c * fmaxf(v, 0.0f);
    }
    atomicAdd(&sacc[j], acc);
}
__global__ void o_final(const float* __restrict__ sacc, const float* __restrict__ W2,
                        const float* __restrict__ b2, float* __restrict__ out, float invN) {
    int j = threadIdx.x;
    float acc = 0.0f;
    #pragma unroll 8
    for (int k = 0; k < F1; ++k) acc += sacc[k] * W2[k * F2 + j];
    out[j] = b2[j] + invN * acc;
}

extern "C" void kernel_launch(void* const* d_in, const int* in_sizes, int n_in,
                              void* d_out, int out_size, void* d_ws, size_t ws_size,
                              hipStream_t stream) {
    const float* W1 = (const float*)d_in[4];
    const float* b1 = (const float*)d_in[5];
    const float* W2 = (const float*)d_in[6];
    const float* b2 = (const float*)d_in[7];
    float* out = (float*)d_out;

    const int n = in_sizes[0] / F0;   // 50000
    const int E = in_sizes[2] / 2;    // 800000
    const int NB = (n + NPB - 1) / NPB;
    const float invN = 1.0f / (float)n;

    // ---- workspace layout (z_ prefix: must not shadow kernel names) ----
    size_t off = 0;
    auto alloc = [&](size_t bytes) { size_t r = off; off += (bytes + 255) & ~(size_t)255; return r; };
    size_t z_bcnt  = alloc(4 * (size_t)MAXB * 4);         // zeroed
    size_t z_bbase = alloc(4 * (size_t)(MAXB + 1) * 4);
    size_t z_bcur  = alloc(4 * (size_t)MAXB * 4);
    size_t z_ebuf  = alloc(4 * (size_t)E * 4);            // [quadrant][E]
    size_t z_dinv  = alloc(2 * (size_t)n * 4);
    size_t z_wout  = alloc(2 * (size_t)n * 4);
    size_t z_y     = alloc(2 * (size_t)n * 24 * 2);
    size_t z_part  = alloc(2 * (size_t)NB * F1 * 4);
    size_t need = off;

    char* ws = (char*)d_ws;
    bool ok = (n <= NPB * MAXB) && (n < 131072) && (E > 0) && (ws_size >= need);

    if (ok) {
        auto mkq = [&](int quad, const int* key, const int* pay) {
            QP q;
            q.key = key; q.pay = pay;
            q.bcnt  = (int*)(ws + z_bcnt)  + (size_t)quad * MAXB;
            q.bbase = (int*)(ws + z_bbase) + (size_t)quad * (MAXB + 1);
            q.bcur  = (int*)(ws + z_bcur)  + (size_t)quad * MAXB;
            q.ebuf  = (unsigned*)(ws + z_ebuf) + (size_t)quad * E;
            return q;
        };
        const int* e0 = (const int*)d_in[2];
        const int* e1 = (const int*)d_in[3];
        // quad 0,1: key=dst (branch 0,1); quad 2,3: key=src
        QP q0 = mkq(0, e0 + E, e0);
        QP q1 = mkq(1, e1 + E, e1);
        QP q2 = mkq(2, e0, e0 + E);
        QP q3 = mkq(3, e1, e1 + E);

        auto mkg = [&](int b, QP qd, QP qs) {
            GP g;
            g.x    = (const float*)d_in[b];
            g.ebd  = qd.ebuf; g.bbd = qd.bbase;
            g.ebs  = qs.ebuf; g.bbs = qs.bbase;
            g.dinv = (float*)(ws + z_dinv) + (size_t)b * n;
            g.wout = (float*)(ws + z_wout) + (size_t)b * n;
            g.y    = (__half*)(ws + z_y) + (size_t)b * n * 24;
            g.part = (float*)(ws + z_part) + (size_t)b * NB * F1;
            g.outp = out + b * F2;
            return g;
        };
        GP g0 = mkg(0, q0, q2);
        GP g1 = mkg(1, q1, q3);

        (void)hipMemsetAsync(ws + z_bcnt, 0, 4 * (size_t)MAXB * 4, stream);
        k_binA<<<dim3(64, 4), BIN_TPB, 0, stream>>>(q0, q1, q2, q3, E);
        k_scan<<<dim3(1, 4), MAXB, 0, stream>>>(q0, q1, q2, q3);
        k_binB<<<dim3((E + BIN_EPB - 1) / BIN_EPB, 4), BIN_TPB, 0, stream>>>(q0, q1, q2, q3, E);
        k_deg2<<<dim3(NB, 2), 256, 0, stream>>>(g0, g1, n);
        k_prep<<<dim3((n * 24 + 255) / 256, 2), 256, 0, stream>>>(g0, g1, n);
        k_wout<<<dim3(NB, 2), 256, 0, stream>>>(g0, g1, n);
        k_agg <<<dim3(NB, 2), 256, 0, stream>>>(g0, g1, W1, b1, n);
        k_fin <<<dim3(1, 2), 1024, 0, stream>>>(g0, g1, W2, b2, invN, NB);
    } else {
        // fallback: round-1 algorithm (atomic scatter), ~4.7 MB
        float* wsf   = (float*)d_ws;
        float* fdeg  = wsf;
        float* fwout = wsf + (size_t)n;
        float* faggx = wsf + 2 * (size_t)n;
        float* fsacc = wsf + 2 * (size_t)n + (size_t)F0 * n;
        float* fdinv = fsacc + F1;
        size_t zero_bytes = ((size_t)23 * n + F1) * sizeof(float);
        for (int b = 0; b < 2; ++b) {
            (void)hipMemsetAsync(wsf, 0, zero_bytes, stream);
            const int* srcp = (const int*)d_in[2 + b];
            const int* dstp = srcp + E;
            const float* x = (const float*)d_in[b];
            o_deg <<<1024, 256, 0, stream>>>(dstp, fdeg, E);
            o_dinv<<<(n + 255) / 256, 256, 0, stream>>>(fdeg, fdinv, n);
            o_edge<<<2048, 256, 0, stream>>>(srcp, dstp, x, fdinv, fwout, faggx, E);
            o_node<<<512, F1, 0, stream>>>(x, faggx, fdinv, fwout, W1, b1, fsacc, n);
            o_final<<<1, F2, 0, stream>>>(fsacc, W2, b2, out + b * F2, invN);
        }
    }
}

// Round 6
// 146.467 us; speedup vs baseline: 4.1641x; 2.1479x over previous
//
#include <hip/hip_runtime.h>
#include <hip/hip_fp16.h>

#define F0 21
#define F1 128
#define F2 64
#define NPB 49            // nodes per bucket; NB = ceil(n/NPB) must be <= MAXB
#define MAXB 1024
#define IDM 0x1FFFFu      // 17-bit node id mask (n < 131072)
#define BIN_TPB 1024
#define BIN_EPT 2
#define BIN_EPB (BIN_TPB * BIN_EPT)   // 2048 edges/block; rank < 4096 guaranteed
#define AGS 24            // agg row stride (floats), 16B-aligned rows
#define ELOC_CAP 1536     // per-block sorted-edge capacity (mean ~784, 5-sigma ~925)

// quadrant bundle: (branch, keying system). sys0 = key by dst, sys1 = key by src
struct QP {
    const int* key;       // [E]
    const int* pay;       // [E]
    int*       bcnt;      // [MAXB]
    int*       bbase;     // [MAXB+1]
    int*       bcur;      // [MAXB]
    unsigned*  ebuf;      // [E] packed (local<<17)|payload_id
};

// per-branch bundle for the later kernels
struct GP {
    const float*    x;     // [n, F0]
    const unsigned* ebd;   // dst-keyed ebuf
    const int*      bbd;   // dst-keyed bbase
    const unsigned* ebs;   // src-keyed ebuf
    const int*      bbs;   // src-keyed bbase
    float*          dinv;  // [n]
    float*          wout;  // [n]
    __half*         y;     // [n*24] fp16 dinv[s]*x[s][k], padded to 24
    float*          part;  // [NB*F1]
    float*          outp;  // [F2]
};

__device__ __forceinline__ QP pickq(QP a, QP b, QP c, QP d) {
    unsigned q = blockIdx.y;
    return q == 0 ? a : q == 1 ? b : q == 2 ? c : d;
}

// ---- phase A: bucket histogram (LDS) + small global merge ----
__global__ void __launch_bounds__(BIN_TPB) k_binA(QP a, QP b, QP c, QP d, int E) {
    QP q = pickq(a, b, c, d);
    __shared__ int h[MAXB];
    int tid = threadIdx.x;
    h[tid] = 0;
    __syncthreads();
    for (int i = blockIdx.x * BIN_TPB + tid; i < E; i += gridDim.x * BIN_TPB)
        atomicAdd(&h[(unsigned)q.key[i] / NPB], 1);
    __syncthreads();
    int v = h[tid];
    if (v) atomicAdd(&q.bcnt[tid], v);
}

// ---- exclusive scan of bucket counts ----
__global__ void __launch_bounds__(MAXB) k_scan(QP a, QP b, QP c, QP d) {
    QP q = pickq(a, b, c, d);
    __shared__ int lds[MAXB];
    int tid = threadIdx.x;
    int v = q.bcnt[tid];
    lds[tid] = v;
    __syncthreads();
    for (int off = 1; off < MAXB; off <<= 1) {
        int t = (tid >= off) ? lds[tid - off] : 0;
        __syncthreads();
        lds[tid] += t;
        __syncthreads();
    }
    int excl = lds[tid] - v;
    q.bbase[tid] = excl;
    q.bcur[tid] = excl;
    if (tid == MAXB - 1) q.bbase[MAXB] = lds[tid];
}

// ---- phase B: scatter edges into buckets (LDS ranks, 1 reservation/(block,bucket)) ----
__global__ void __launch_bounds__(BIN_TPB) k_binB(QP a, QP b, QP c, QP d, int E) {
    QP q = pickq(a, b, c, d);
    __shared__ int h[MAXB];
    __shared__ int base[MAXB];
    int tid = threadIdx.x;
    h[tid] = 0;
    __syncthreads();
    int e0 = blockIdx.x * BIN_EPB;
    unsigned pk[BIN_EPT], br[BIN_EPT];
    #pragma unroll
    for (int i = 0; i < BIN_EPT; ++i) {
        int e = e0 + i * BIN_TPB + tid;
        if (e < E) {
            int k = q.key[e], p = q.pay[e];
            unsigned bk = (unsigned)k / NPB;
            int r = atomicAdd(&h[bk], 1);
            pk[i] = ((unsigned)(k - (int)bk * NPB) << 17) | (unsigned)p;
            br[i] = (bk << 12) | (unsigned)r;
        }
    }
    __syncthreads();
    int c0 = h[tid];
    if (c0) base[tid] = atomicAdd(&q.bcur[tid], c0);
    __syncthreads();
    #pragma unroll
    for (int i = 0; i < BIN_EPT; ++i) {
        int e = e0 + i * BIN_TPB + tid;
        if (e < E) {
            unsigned bk = br[i] >> 12, r = br[i] & 4095u;
            q.ebuf[base[bk] + r] = pk[i];
        }
    }
}

// ---- per dst-bucket degree count from sorted edges -> dinv (no global atomics) ----
__global__ void __launch_bounds__(256) k_deg2(GP g0, GP g1, int n) {
    GP g = blockIdx.y ? g1 : g0;
    __shared__ int cnt[NPB];
    int tid = threadIdx.x;
    if (tid < NPB) cnt[tid] = 0;
    __syncthreads();
    int s0 = g.bbd[blockIdx.x], s1 = g.bbd[blockIdx.x + 1];
    for (int e = s0 + tid; e < s1; e += 256) atomicAdd(&cnt[g.ebd[e] >> 17], 1);
    __syncthreads();
    int node = blockIdx.x * NPB + tid;
    if (tid < NPB && node < n) g.dinv[node] = rsqrtf(1.0f + (float)cnt[tid]);
}

// ---- y[s][k] = fp16(dinv[s] * x[s][k]), rows padded to 24 halfs ----
__global__ void __launch_bounds__(256) k_prep(GP g0, GP g1, int n) {
    GP g = blockIdx.y ? g1 : g0;
    int i = blockIdx.x * 256 + threadIdx.x;
    int total = n * 24;
    if (i < total) {
        int s = i / 24;
        int k = i - s * 24;
        float v = (k < F0) ? g.dinv[s] * g.x[(size_t)s * F0 + k] : 0.0f;
        g.y[i] = __float2half(v);
    }
}

// ---- per src-bucket: wout[s] = sum(dinv[dst]) from src-sorted edges ----
__global__ void __launch_bounds__(256) k_wout(GP g0, GP g1, int n) {
    GP g = blockIdx.y ? g1 : g0;
    __shared__ float wl[NPB];
    int tid = threadIdx.x;
    if (tid < NPB) wl[tid] = 0.0f;
    __syncthreads();
    int s0 = g.bbs[blockIdx.x], s1 = g.bbs[blockIdx.x + 1];
    for (int e = s0 + tid; e < s1; e += 256) {
        unsigned u = g.ebs[e];
        atomicAdd(&wl[u >> 17], g.dinv[u & IDM]);
    }
    __syncthreads();
    int node = blockIdx.x * NPB + tid;
    if (tid < NPB && node < n) g.wout[node] = wl[tid];
}

// ---- main: block-local counting sort -> register aggregation -> fused W1 reduce ----
// Grid is 1-D: blocks with (bid&7)<4 run branch 0, others branch 1 (XCD L2 split).
__global__ void __launch_bounds__(256) k_agg(GP g0, GP g1,
        const float* __restrict__ W1, const float* __restrict__ b1v, int n, int NB) {
    unsigned bid = blockIdx.x;
    unsigned qq = bid >> 3, rr = bid & 7;
    int branch = (rr >= 4);
    int slot = (int)(qq * 4 + (rr & 3));
    if (slot >= NB) return;                       // uniform per block
    GP g = branch ? g1 : g0;

    __shared__ float agg[NPB * AGS];              // 4704 B, rows 16B-aligned
    __shared__ int   eloc[ELOC_CAP];              // 6144 B
    __shared__ int   off[NPB + 1];
    __shared__ int   cur[NPB];
    __shared__ float red[256];

    int tid = threadIdx.x;
    int j = tid & (F1 - 1), half = tid >> 7;
    int s0 = g.bbd[slot], s1 = g.bbd[slot + 1];
    int cnt = s1 - s0;
    int node0 = slot * NPB;
    int nn = min(NPB, n - node0);

    // W1 column -> registers (coalesced, L2-hot), zero-padded to 24
    float w[AGS];
    #pragma unroll
    for (int k = 0; k < F0; ++k) w[k] = W1[k * F1 + j];
    w[21] = w[22] = w[23] = 0.0f;
    float bj = b1v[j];

    const uint4* yb = (const uint4*)g.y;

    if (tid < NPB) cur[tid] = 0;
    __syncthreads();

    if (cnt <= ELOC_CAP) {
        // phase 1: counting sort by node-local id (2 LDS atomics/edge vs 21)
        for (int e = s0 + tid; e < s1; e += 256)
            atomicAdd(&cur[g.ebd[e] >> 17], 1);
        __syncthreads();
        if (tid == 0) {
            int acc = 0;
            for (int t = 0; t < NPB; ++t) { off[t] = acc; acc += cur[t]; }
            off[NPB] = acc;
        }
        __syncthreads();
        if (tid < NPB) cur[tid] = off[tid];
        __syncthreads();
        for (int e = s0 + tid; e < s1; e += 256) {
            unsigned u = g.ebd[e];
            int p = atomicAdd(&cur[u >> 17], 1);
            eloc[p] = (int)(u & IDM);
        }
        __syncthreads();
        // phase 2: 3 threads/node, register accumulate (self row = extra iteration)
        if (tid < 3 * NPB) {
            int tl = tid / 3, kc = tid - (tid / 3) * 3;
            if (tl < nn) {
                int node = node0 + tl;
                float a[8] = {0, 0, 0, 0, 0, 0, 0, 0};
                int eA = off[tl], eB = off[tl + 1];
                for (int e = eA; e <= eB; ++e) {
                    int s = (e < eB) ? eloc[e] : node;     // last iter: self row
                    uint4 v = yb[(size_t)s * 3 + kc];
                    const unsigned* vw = reinterpret_cast<const unsigned*>(&v);
                    #pragma unroll
                    for (int m = 0; m < 4; ++m) {
                        float2 f = __half22float2(*reinterpret_cast<const __half2*>(&vw[m]));
                        a[2 * m]     += f.x;
                        a[2 * m + 1] += f.y;
                    }
                }
                float* ag = agg + tl * AGS + kc * 8;
                #pragma unroll
                for (int m = 0; m < 8; ++m) ag[m] = a[m];  // pads are 0 in y -> agg pads 0
            }
        }
    } else {
        // oversized bucket (skewed input): old atomic path, still correct
        for (int i = tid; i < NPB * AGS; i += 256) agg[i] = 0.0f;
        __syncthreads();
        for (int e = s0 + tid; e < s1; e += 256) {
            unsigned u = g.ebd[e];
            int s = (int)(u & IDM);
            int tl = (int)(u >> 17);
            uint4 A = yb[(size_t)s * 3 + 0];
            uint4 B = yb[(size_t)s * 3 + 1];
            uint4 C = yb[(size_t)s * 3 + 2];
            float* ag = agg + tl * AGS;
            const unsigned wv[12] = {A.x, A.y, A.z, A.w, B.x, B.y, B.z, B.w, C.x, C.y, C.z, C.w};
            #pragma unroll
            for (int m = 0; m < 10; ++m) {
                float2 f = __half22float2(*reinterpret_cast<const __half2*>(&wv[m]));
                atomicAdd(&ag[2 * m], f.x);
                atomicAdd(&ag[2 * m + 1], f.y);
            }
            atomicAdd(&ag[20], __low2float(*reinterpret_cast<const __half2*>(&wv[10])));
        }
        __syncthreads();
        if (tid < 3 * NPB) {                       // self rows, exclusive-owner adds
            int tl = tid / 3, kc = tid - (tid / 3) * 3;
            if (tl < nn) {
                uint4 v = yb[(size_t)(node0 + tl) * 3 + kc];
                const unsigned* vw = reinterpret_cast<const unsigned*>(&v);
                float* ag = agg + tl * AGS + kc * 8;
                #pragma unroll
                for (int m = 0; m < 4; ++m) {
                    float2 f = __half22float2(*reinterpret_cast<const __half2*>(&vw[m]));
                    ag[2 * m]     += f.x;
                    ag[2 * m + 1] += f.y;
                }
            }
        }
    }
    __syncthreads();

    // phase 3: v_j = b1[j] + di * (agg[tl] . W1[:,j]); acc += c * relu(v)
    float acc = 0.0f;
    for (int tl = half; tl < nn; tl += 2) {
        int node = node0 + tl;
        float di = g.dinv[node];                   // broadcast
        float co = di * g.wout[node] + di * di;
        float dot = 0.0f;
        #pragma unroll
        for (int m = 0; m < 6; ++m) {              // 6 x ds_read_b128 broadcast
            float4 v4 = *reinterpret_cast<const float4*>(&agg[tl * AGS + m * 4]);
            dot += v4.x * w[4 * m] + v4.y * w[4 * m + 1]
                 + v4.z * w[4 * m + 2] + v4.w * w[4 * m + 3];
        }
        acc += co * fmaxf(bj + di * dot, 0.0f);
    }
    red[tid] = acc;
    __syncthreads();
    if (half == 0) g.part[(size_t)slot * F1 + j] = red[j] + red[j + F1];
}

// ---- reduce part over buckets, then out = b2 + invN * (sacc @ W2) ----
__global__ void __launch_bounds__(1024) k_fin(GP g0, GP g1,
        const float* __restrict__ W2, const float* __restrict__ b2,
        float invN, int NB) {
    GP g = blockIdx.y ? g1 : g0;
    __shared__ float red[1024];
    __shared__ float sv[F1];
    int tid = threadIdx.x;
    int j = tid & (F1 - 1), h = tid >> 7;   // 8 slices
    float a = 0.0f;
    for (int r = h; r < NB; r += 8) a += g.part[(size_t)r * F1 + j];
    red[tid] = a;
    __syncthreads();
    for (int s = 4; s >= 1; s >>= 1) {
        if (h < s) red[tid] += red[tid + s * F1];
        __syncthreads();
    }
    if (tid < F1) sv[tid] = red[tid];
    __syncthreads();
    if (tid < F2) {
        float o = 0.0f;
        #pragma unroll 8
        for (int k = 0; k < F1; ++k) o += sv[k] * W2[k * F2 + tid];
        g.outp[tid] = b2[tid] + invN * o;
    }
}

// ---------------- fallback (round-1 algorithm, ~4.7 MB ws) ----------------
__global__ void o_deg(const int* __restrict__ dst, float* __restrict__ deg, int E) {
    int i = blockIdx.x * blockDim.x + threadIdx.x;
    int stride = gridDim.x * blockDim.x;
    for (; i < E; i += stride) atomicAdd(&deg[dst[i]], 1.0f);
}
__global__ void o_dinv(const float* __restrict__ deg, float* __restrict__ dinv, int n) {
    int i = blockIdx.x * blockDim.x + threadIdx.x;
    if (i < n) dinv[i] = rsqrtf(deg[i] + 1.0f);
}
__global__ void o_edge(const int* __restrict__ src, const int* __restrict__ dst,
                       const float* __restrict__ x, const float* __restrict__ dinv,
                       float* __restrict__ wout, float* __restrict__ aggx, int E) {
    int total = E * F0;
    int i = blockIdx.x * blockDim.x + threadIdx.x;
    int stride = gridDim.x * blockDim.x;
    for (; i < total; i += stride) {
        int e = i / F0;
        int k = i - e * F0;
        int s = src[e], t = dst[e];
        float ds = dinv[s], dt = dinv[t];
        if (k == 0) atomicAdd(&wout[s], dt);
        atomicAdd(&aggx[t * F0 + k], x[s * F0 + k] * (ds * dt));
    }
}
__global__ void __launch_bounds__(F1) o_node(
        const float* __restrict__ x, const float* __restrict__ aggx,
        const float* __restrict__ dinv, const float* __restrict__ wout,
        const float* __restrict__ W1, const float* __restrict__ b1,
        float* __restrict__ sacc, int n) {
    __shared__ float w1s[F0 * F1];
    __shared__ float b1s[F1];
    int j = threadIdx.x;
    for (int idx = j; idx < F0 * F1; idx += F1) w1s[idx] = W1[idx];
    b1s[j] = b1[j];
    __syncthreads();
    float acc = 0.0f;
    for (int node = blockIdx.x; node < n; node += gridDim.x) {
        float di = dinv[node];
        float di2 = di * di;
        float c = di * wout[node] + di2;
        const float* xr = x + (size_t)node * F0;
        const float* ar = aggx + (size_t)node * F0;
        float v = b1s[j];
        #pragma unroll
        for (int k = 0; k < F0; ++k) v += (ar[k] + xr[k] * di2) * w1s[k * F1 + j];
        acc += c * fmaxf(v, 0.0f);
    }
    atomicAdd(&sacc[j], acc);
}
__global__ void o_final(const float* __restrict__ sacc, const float* __restrict__ W2,
                        const float* __restrict__ b2, float* __restrict__ out, float invN) {
    int j = threadIdx.x;
    float acc = 0.0f;
    #pragma unroll 8
    for (int k = 0; k < F1; ++k) acc += sacc[k] * W2[k * F2 + j];
    out[j] = b2[j] + invN * acc;
}

extern "C" void kernel_launch(void* const* d_in, const int* in_sizes, int n_in,
                              void* d_out, int out_size, void* d_ws, size_t ws_size,
                              hipStream_t stream) {
    const float* W1 = (const float*)d_in[4];
    const float* b1 = (const float*)d_in[5];
    const float* W2 = (const float*)d_in[6];
    const float* b2 = (const float*)d_in[7];
    float* out = (float*)d_out;

    const int n = in_sizes[0] / F0;   // 50000
    const int E = in_sizes[2] / 2;    // 800000
    const int NB = (n + NPB - 1) / NPB;
    const float invN = 1.0f / (float)n;

    // ---- workspace layout (z_ prefix: must not shadow kernel names) ----
    size_t off = 0;
    auto alloc = [&](size_t bytes) { size_t r = off; off += (bytes + 255) & ~(size_t)255; return r; };
    size_t z_bcnt  = alloc(4 * (size_t)MAXB * 4);         // zeroed
    size_t z_bbase = alloc(4 * (size_t)(MAXB + 1) * 4);
    size_t z_bcur  = alloc(4 * (size_t)MAXB * 4);
    size_t z_ebuf  = alloc(4 * (size_t)E * 4);            // [quadrant][E]
    size_t z_dinv  = alloc(2 * (size_t)n * 4);
    size_t z_wout  = alloc(2 * (size_t)n * 4);
    size_t z_y     = alloc(2 * (size_t)n * 24 * 2);
    size_t z_part  = alloc(2 * (size_t)NB * F1 * 4);
    size_t need = off;

    char* ws = (char*)d_ws;
    bool ok = (n <= NPB * MAXB) && (n < 131072) && (E > 0) && (ws_size >= need);

    if (ok) {
        auto mkq = [&](int quad, const int* key, const int* pay) {
            QP q;
            q.key = key; q.pay = pay;
            q.bcnt  = (int*)(ws + z_bcnt)  + (size_t)quad * MAXB;
            q.bbase = (int*)(ws + z_bbase) + (size_t)quad * (MAXB + 1);
            q.bcur  = (int*)(ws + z_bcur)  + (size_t)quad * MAXB;
            q.ebuf  = (unsigned*)(ws + z_ebuf) + (size_t)quad * E;
            return q;
        };
        const int* e0 = (const int*)d_in[2];
        const int* e1 = (const int*)d_in[3];
        // quad 0,1: key=dst (branch 0,1); quad 2,3: key=src
        QP q0 = mkq(0, e0 + E, e0);
        QP q1 = mkq(1, e1 + E, e1);
        QP q2 = mkq(2, e0, e0 + E);
        QP q3 = mkq(3, e1, e1 + E);

        auto mkg = [&](int b, QP qd, QP qs) {
            GP g;
            g.x    = (const float*)d_in[b];
            g.ebd  = qd.ebuf; g.bbd = qd.bbase;
            g.ebs  = qs.ebuf; g.bbs = qs.bbase;
            g.dinv = (float*)(ws + z_dinv) + (size_t)b * n;
            g.wout = (float*)(ws + z_wout) + (size_t)b * n;
            g.y    = (__half*)(ws + z_y) + (size_t)b * n * 24;
            g.part = (float*)(ws + z_part) + (size_t)b * NB * F1;
            g.outp = out + b * F2;
            return g;
        };
        GP g0 = mkg(0, q0, q2);
        GP g1 = mkg(1, q1, q3);

        (void)hipMemsetAsync(ws + z_bcnt, 0, 4 * (size_t)MAXB * 4, stream);
        k_binA<<<dim3(64, 4), BIN_TPB, 0, stream>>>(q0, q1, q2, q3, E);
        k_scan<<<dim3(1, 4), MAXB, 0, stream>>>(q0, q1, q2, q3);
        k_binB<<<dim3((E + BIN_EPB - 1) / BIN_EPB, 4), BIN_TPB, 0, stream>>>(q0, q1, q2, q3, E);
        k_deg2<<<dim3(NB, 2), 256, 0, stream>>>(g0, g1, n);
        k_prep<<<dim3((n * 24 + 255) / 256, 2), 256, 0, stream>>>(g0, g1, n);
        k_wout<<<dim3(NB, 2), 256, 0, stream>>>(g0, g1, n);
        int NB4 = (NB + 3) / 4;
        k_agg <<<dim3(8 * NB4), 256, 0, stream>>>(g0, g1, W1, b1, n, NB);
        k_fin <<<dim3(1, 2), 1024, 0, stream>>>(g0, g1, W2, b2, invN, NB);
    } else {
        // fallback: round-1 algorithm (atomic scatter), ~4.7 MB
        float* wsf   = (float*)d_ws;
        float* fdeg  = wsf;
        float* fwout = wsf + (size_t)n;
        float* faggx = wsf + 2 * (size_t)n;
        float* fsacc = wsf + 2 * (size_t)n + (size_t)F0 * n;
        float* fdinv = fsacc + F1;
        size_t zero_bytes = ((size_t)23 * n + F1) * sizeof(float);
        for (int b = 0; b < 2; ++b) {
            (void)hipMemsetAsync(wsf, 0, zero_bytes, stream);
            const int* srcp = (const int*)d_in[2 + b];
            const int* dstp = srcp + E;
            const float* x = (const float*)d_in[b];
            o_deg <<<1024, 256, 0, stream>>>(dstp, fdeg, E);
            o_dinv<<<(n + 255) / 256, 256, 0, stream>>>(fdeg, fdinv, n);
            o_edge<<<2048, 256, 0, stream>>>(srcp, dstp, x, fdinv, fwout, faggx, E);
            o_node<<<512, F1, 0, stream>>>(x, faggx, fdinv, fwout, W1, b1, fsacc, n);
            o_final<<<1, F2, 0, stream>>>(fsacc, W2, b2, out + b * F2, invN);
        }
    }
}